// Round 6
// baseline (687.200 us; speedup 1.0000x reference)
//
#include <hip/hip_runtime.h>
#include <hip/hip_bf16.h>

#define N_NODES 50000
#define N_EDGES 800000
#define DIM     256
#define NLAYERS 4
#define EPS     1e-5f
#define SCAN_B  196   // ceil(50000/256)
#define MASK40  ((1ULL << 40) - 1)
#define EPACK_CAP (N_EDGES + 15 * N_NODES + 32)   // CSR padded to 16

typedef __bf16 bf16x8 __attribute__((ext_vector_type(8)));
typedef float  f32x4  __attribute__((ext_vector_type(4)));
typedef unsigned short u16x8 __attribute__((ext_vector_type(8)));

__device__ __forceinline__ unsigned short f2b(float f) {
    __hip_bfloat16 h = __float2bfloat16(f);
    return __builtin_bit_cast(unsigned short, h);
}
__device__ __forceinline__ float b2f(unsigned short u) {
    unsigned int v = ((unsigned int)u) << 16;
    return __builtin_bit_cast(float, v);
}
__device__ __forceinline__ float gelu_exact(float x) {
    return 0.5f * x * (1.0f + erff(x * 0.70710678118654752f));
}

// ---- setup kernels ------------------------------------------------------
// One packed u64 atomic per edge: bits [40,64) = count, [0,40) = sum(w)*2^32.
// Returned old value's count field = this edge's rank within its dst row.
__global__ __launch_bounds__(256) void hist_kernel(const int* __restrict__ dst,
                                                   const float* __restrict__ w,
                                                   unsigned long long* __restrict__ cnt64,
                                                   int* __restrict__ rank) {
    int e = blockIdx.x * 256 + threadIdx.x;
    if (e >= N_EDGES) return;
    int d = dst[e];
    unsigned long long wfix = (unsigned long long)(w[e] * 4294967296.0f);
    unsigned long long old = atomicAdd(&cnt64[d], (1ULL << 40) | wfix);
    rank[e] = (int)(old >> 40);
}

// dinv = rsqrt(1 + sum(w)) ; block-sum of padded counts (pad to 16)
__global__ __launch_bounds__(256) void scan_a_kernel(const unsigned long long* __restrict__ cnt64,
                                                     float* __restrict__ dinv,
                                                     int* __restrict__ bsum) {
    __shared__ int l[256];
    int i = blockIdx.x * 256 + threadIdx.x;
    int pc = 0;
    if (i < N_NODES) {
        unsigned long long v = cnt64[i];
        int cnt = (int)(v >> 40);
        float sw = (float)(v & MASK40) * 2.3283064365386963e-10f;  // *2^-32
        dinv[i] = rsqrtf(1.0f + sw);
        pc = (cnt + 15) & ~15;
    }
    l[threadIdx.x] = pc;
    __syncthreads();
    for (int o = 128; o > 0; o >>= 1) {
        if (threadIdx.x < o) l[threadIdx.x] += l[threadIdx.x + o];
        __syncthreads();
    }
    if (threadIdx.x == 0) bsum[blockIdx.x] = l[0];
}

__global__ __launch_bounds__(256) void scan_b_kernel(const int* __restrict__ bsum,
                                                     int* __restrict__ boff,
                                                     int* __restrict__ rowptr) {
    __shared__ int l[256];
    int t = threadIdx.x;
    l[t] = (t < SCAN_B) ? bsum[t] : 0;
    __syncthreads();
    if (t == 0) {
        int run = 0;
        for (int j = 0; j < SCAN_B; ++j) { int v = l[j]; l[j] = run; run += v; }
        rowptr[N_NODES] = run;  // total padded entries
    }
    __syncthreads();
    boff[t] = l[t];
}

__global__ __launch_bounds__(256) void scan_c_kernel(const unsigned long long* __restrict__ cnt64,
                                                     const int* __restrict__ boff,
                                                     int* __restrict__ rowptr) {
    __shared__ int l[256];
    int i = blockIdx.x * 256 + threadIdx.x;
    int pc = 0;
    if (i < N_NODES) {
        int cnt = (int)(cnt64[i] >> 40);
        pc = (cnt + 15) & ~15;
    }
    l[threadIdx.x] = pc;
    __syncthreads();
    if (threadIdx.x == 0) {
        int run = 0;
        for (int j = 0; j < 256; ++j) { int v = l[j]; l[j] = run; run += v; }
    }
    __syncthreads();
    if (i < N_NODES) rowptr[i] = boff[blockIdx.x] + l[threadIdx.x];
}

// No atomics: position = rowptr[dst] + rank.  epack.x = src byte-offset (src*512).
__global__ __launch_bounds__(256) void fill_kernel(const int* __restrict__ src,
                                                   const int* __restrict__ dst,
                                                   const float* __restrict__ w,
                                                   const float* __restrict__ dinv,
                                                   const int* __restrict__ rowptr,
                                                   const int* __restrict__ rank,
                                                   int2* __restrict__ epack) {
    int e = blockIdx.x * 256 + threadIdx.x;
    if (e >= N_EDGES) return;
    int s = src[e], d = dst[e];
    float c = dinv[s] * w[e] * dinv[d];
    int p = rowptr[d] + rank[e];
    epack[p] = make_int2(s << 9, __float_as_int(c));
}

// conv_w[l][k][n] (l<4) and post_w[k][n] (slot 4) -> Wt[l][n][k] bf16
__global__ __launch_bounds__(256) void convw_kernel(const float* __restrict__ conv_w,
                                                    const float* __restrict__ post_w,
                                                    unsigned short* __restrict__ Wt) {
    int idx = blockIdx.x * 256 + threadIdx.x;
    if (idx >= 5 * 65536) return;
    int m = idx >> 16;
    int r = idx & 65535;
    int n = r >> 8;
    int k = r & 255;
    float v = (m < 4) ? conv_w[m * 65536 + k * 256 + n] : post_w[k * 256 + n];
    Wt[idx] = f2b(v);
}

// ---- per-layer kernels --------------------------------------------------
// wave-per-row: Z = bf16(LN(emb)), Hbf = bf16(emb)  (used once)
__global__ __launch_bounds__(256) void ln_cast_kernel(const float* __restrict__ H,
                                                      const float* __restrict__ lnw,
                                                      const float* __restrict__ lnb,
                                                      unsigned short* __restrict__ Z,
                                                      unsigned short* __restrict__ Hbf) {
    int row = blockIdx.x * 4 + (threadIdx.x >> 6);
    int lane = threadIdx.x & 63;
    const float4 x = *(const float4*)(H + (size_t)row * DIM + lane * 4);
    float s = x.x + x.y + x.z + x.w;
    for (int o = 32; o > 0; o >>= 1) s += __shfl_xor(s, o);
    float mu = s * (1.0f / DIM);
    float d0 = x.x - mu, d1 = x.y - mu, d2 = x.z - mu, d3 = x.w - mu;
    float v = d0 * d0 + d1 * d1 + d2 * d2 + d3 * d3;
    for (int o = 32; o > 0; o >>= 1) v += __shfl_xor(v, o);
    float rs = rsqrtf(v * (1.0f / DIM) + EPS);
    const float4 ww = *(const float4*)(lnw + lane * 4);
    const float4 bb = *(const float4*)(lnb + lane * 4);
    ushort4 o4;
    o4.x = f2b(d0 * rs * ww.x + bb.x);
    o4.y = f2b(d1 * rs * ww.y + bb.y);
    o4.z = f2b(d2 * rs * ww.z + bb.z);
    o4.w = f2b(d3 * rs * ww.w + bb.w);
    *(ushort4*)(Z + (size_t)row * DIM + lane * 4) = o4;
    ushort4 h4;
    h4.x = f2b(x.x); h4.y = f2b(x.y); h4.z = f2b(x.z); h4.w = f2b(x.w);
    *(ushort4*)(Hbf + (size_t)row * DIM + lane * 4) = h4;
}

// ---- GEMM, transposed-operand form (weights = MFMA A-operand) -----------
template <int MODE>
__device__ __forceinline__ void gemm_body(const unsigned short* __restrict__ A,
                                          const unsigned short* __restrict__ Bt,
                                          void* __restrict__ Cout,
                                          const float* __restrict__ bias) {
    int tid = threadIdx.x;
    int wave = tid >> 6;
    int lane = tid & 63;
    int q = lane >> 4;
    int c16 = lane & 15;
    int mbase = blockIdx.x * 64;   // node base
    int cbase = wave * 64;         // channel base

    const unsigned short* aptr[4];
    #pragma unroll
    for (int nt = 0; nt < 4; ++nt) {
        int row = mbase + nt * 16 + c16;
        if (row >= N_NODES) row = N_NODES - 1;
        aptr[nt] = A + (size_t)row * DIM;
    }
    const unsigned short* wptr[4];
    #pragma unroll
    for (int ct = 0; ct < 4; ++ct)
        wptr[ct] = Bt + (size_t)(cbase + ct * 16 + c16) * DIM;

    f32x4 acc[4][4] = {};
    #pragma unroll 2
    for (int k0 = 0; k0 < DIM; k0 += 32) {
        bf16x8 nf[4], wf[4];
        #pragma unroll
        for (int nt = 0; nt < 4; ++nt)
            nf[nt] = __builtin_bit_cast(bf16x8, *(const u16x8*)(aptr[nt] + k0 + q * 8));
        #pragma unroll
        for (int ct = 0; ct < 4; ++ct)
            wf[ct] = __builtin_bit_cast(bf16x8, *(const u16x8*)(wptr[ct] + k0 + q * 8));
        #pragma unroll
        for (int nt = 0; nt < 4; ++nt)
            #pragma unroll
            for (int ct = 0; ct < 4; ++ct)
                acc[nt][ct] = __builtin_amdgcn_mfma_f32_16x16x32_bf16(wf[ct], nf[nt], acc[nt][ct], 0, 0, 0);
    }

    float4 bb[4];
    if (MODE == 1) {
        #pragma unroll
        for (int ct = 0; ct < 4; ++ct)
            bb[ct] = *(const float4*)(bias + cbase + ct * 16 + q * 4);
    }
    #pragma unroll
    for (int nt = 0; nt < 4; ++nt) {
        int node = mbase + nt * 16 + c16;
        if (node >= N_NODES) continue;
        #pragma unroll
        for (int ct = 0; ct < 4; ++ct) {
            int chan = cbase + ct * 16 + q * 4;
            if (MODE == 0) {
                unsigned short* C = (unsigned short*)Cout;
                ushort4 o4;
                o4.x = f2b(acc[nt][ct][0]);
                o4.y = f2b(acc[nt][ct][1]);
                o4.z = f2b(acc[nt][ct][2]);
                o4.w = f2b(acc[nt][ct][3]);
                *(ushort4*)(C + (size_t)node * DIM + chan) = o4;
            } else {
                float* C = (float*)Cout;
                float4 o;
                o.x = acc[nt][ct][0] + bb[ct].x;
                o.y = acc[nt][ct][1] + bb[ct].y;
                o.z = acc[nt][ct][2] + bb[ct].z;
                o.w = acc[nt][ct][3] + bb[ct].w;
                *(float4*)(C + (size_t)node * DIM + chan) = o;
            }
        }
    }
}

__global__ __launch_bounds__(256) void gemm_bf16_kernel(const unsigned short* __restrict__ A,
                                                        const unsigned short* __restrict__ Bt,
                                                        unsigned short* __restrict__ C) {
    gemm_body<0>(A, Bt, C, nullptr);
}

__global__ __launch_bounds__(256) void gemm_f32_kernel(const unsigned short* __restrict__ A,
                                                       const unsigned short* __restrict__ Bt,
                                                       float* __restrict__ C,
                                                       const float* __restrict__ bias) {
    gemm_body<1>(A, Bt, C, bias);
}

// wave-per-node CSR aggregation over rows PADDED TO 16 (pads: off=0, coef=0).
// Each half-wave (32 lanes x 16B) runs an 8-deep gather chain -> 16 gathers
// in flight per wave. Residual H is bf16, updated in place. Fused bias +
// exact GELU + residual + next-layer LN/cast -> Z16 bf16.
__global__ __launch_bounds__(256) void agg_kernel(const char* __restrict__ ZW,
                                                  unsigned short* __restrict__ Hbf,
                                                  const float* __restrict__ bias,
                                                  const int* __restrict__ rowptr,
                                                  const int2* __restrict__ epack,
                                                  const float* __restrict__ dinv,
                                                  const float* __restrict__ lnw,
                                                  const float* __restrict__ lnb,
                                                  unsigned short* __restrict__ Zout,
                                                  int doLN, int writeH) {
    int node = blockIdx.x * 4 + (threadIdx.x >> 6);
    int lane = threadIdx.x & 63;
    int g = lane >> 5;            // half id
    int colB = (lane & 31) * 16;  // byte offset of this lane's 8 bf16

    float di = dinv[node];
    float scg = (g == 0) ? di * di : 0.0f;   // self-loop only in half 0
    const u16x8 zs = *(const u16x8*)(ZW + node * 512 + colB);
    float a[8];
    #pragma unroll
    for (int j = 0; j < 8; ++j) a[j] = scg * b2f(zs[j]);

    int e0 = rowptr[node], e1 = rowptr[node + 1];
    for (int e = e0; e < e1; e += 16) {
        const int2* pp = epack + e + 8 * g;
        const int4 q0 = *(const int4*)pp;        // edges 0,1
        const int4 q1 = *(const int4*)(pp + 2);  // edges 2,3
        const int4 q2 = *(const int4*)(pp + 4);  // edges 4,5
        const int4 q3 = *(const int4*)(pp + 6);  // edges 6,7
        const u16x8 v0 = *(const u16x8*)(ZW + q0.x + colB);
        const u16x8 v1 = *(const u16x8*)(ZW + q0.z + colB);
        const u16x8 v2 = *(const u16x8*)(ZW + q1.x + colB);
        const u16x8 v3 = *(const u16x8*)(ZW + q1.z + colB);
        const u16x8 v4 = *(const u16x8*)(ZW + q2.x + colB);
        const u16x8 v5 = *(const u16x8*)(ZW + q2.z + colB);
        const u16x8 v6 = *(const u16x8*)(ZW + q3.x + colB);
        const u16x8 v7 = *(const u16x8*)(ZW + q3.z + colB);
        float c0 = __int_as_float(q0.y), c1 = __int_as_float(q0.w);
        float c2 = __int_as_float(q1.y), c3 = __int_as_float(q1.w);
        float c4 = __int_as_float(q2.y), c5 = __int_as_float(q2.w);
        float c6 = __int_as_float(q3.y), c7 = __int_as_float(q3.w);
        #pragma unroll
        for (int j = 0; j < 8; ++j) {
            a[j] += c0 * b2f(v0[j]);
            a[j] += c1 * b2f(v1[j]);
            a[j] += c2 * b2f(v2[j]);
            a[j] += c3 * b2f(v3[j]);
            a[j] += c4 * b2f(v4[j]);
            a[j] += c5 * b2f(v5[j]);
            a[j] += c6 * b2f(v6[j]);
            a[j] += c7 * b2f(v7[j]);
        }
    }
    // combine the two halves
    #pragma unroll
    for (int j = 0; j < 8; ++j) a[j] += __shfl_xor(a[j], 32);

    int col0 = (lane & 31) * 8;
    const float4 bb0 = *(const float4*)(bias + col0);
    const float4 bb1 = *(const float4*)(bias + col0 + 4);
    const u16x8 hv = *(const u16x8*)(Hbf + (size_t)node * DIM + col0);
    float o[8];
    o[0] = b2f(hv[0]) + gelu_exact(a[0] + bb0.x);
    o[1] = b2f(hv[1]) + gelu_exact(a[1] + bb0.y);
    o[2] = b2f(hv[2]) + gelu_exact(a[2] + bb0.z);
    o[3] = b2f(hv[3]) + gelu_exact(a[3] + bb0.w);
    o[4] = b2f(hv[4]) + gelu_exact(a[4] + bb1.x);
    o[5] = b2f(hv[5]) + gelu_exact(a[5] + bb1.y);
    o[6] = b2f(hv[6]) + gelu_exact(a[6] + bb1.z);
    o[7] = b2f(hv[7]) + gelu_exact(a[7] + bb1.w);

    if (writeH && g == 0) {
        u16x8 hw;
        #pragma unroll
        for (int j = 0; j < 8; ++j) hw[j] = f2b(o[j]);
        *(u16x8*)(Hbf + (size_t)node * DIM + col0) = hw;
    }

    float y[8];
    #pragma unroll
    for (int j = 0; j < 8; ++j) y[j] = o[j];
    if (doLN) {
        float s = 0.0f;
        #pragma unroll
        for (int j = 0; j < 8; ++j) s += o[j];
        for (int off = 16; off > 0; off >>= 1) s += __shfl_xor(s, off);
        float mu = s * (1.0f / DIM);
        float v = 0.0f;
        float d[8];
        #pragma unroll
        for (int j = 0; j < 8; ++j) { d[j] = o[j] - mu; v += d[j] * d[j]; }
        for (int off = 16; off > 0; off >>= 1) v += __shfl_xor(v, off);
        float rs = rsqrtf(v * (1.0f / DIM) + EPS);
        const float4 ww0 = *(const float4*)(lnw + col0);
        const float4 ww1 = *(const float4*)(lnw + col0 + 4);
        const float4 lb0 = *(const float4*)(lnb + col0);
        const float4 lb1 = *(const float4*)(lnb + col0 + 4);
        y[0] = d[0] * rs * ww0.x + lb0.x;
        y[1] = d[1] * rs * ww0.y + lb0.y;
        y[2] = d[2] * rs * ww0.z + lb0.z;
        y[3] = d[3] * rs * ww0.w + lb0.w;
        y[4] = d[4] * rs * ww1.x + lb1.x;
        y[5] = d[5] * rs * ww1.y + lb1.y;
        y[6] = d[6] * rs * ww1.z + lb1.z;
        y[7] = d[7] * rs * ww1.w + lb1.w;
    }
    if (g == 0) {
        u16x8 z;
        #pragma unroll
        for (int j = 0; j < 8; ++j) z[j] = f2b(y[j]);
        *(u16x8*)(Zout + (size_t)node * DIM + col0) = z;
    }
}

// ---- launch -------------------------------------------------------------
extern "C" void kernel_launch(void* const* d_in, const int* in_sizes, int n_in,
                              void* d_out, int out_size, void* d_ws, size_t ws_size,
                              hipStream_t stream) {
    const int*   ei     = (const int*)d_in[1];
    const int*   src    = ei;
    const int*   dst    = ei + N_EDGES;
    const float* ew     = (const float*)d_in[2];
    const float* emb    = (const float*)d_in[3];
    const float* ln_w   = (const float*)d_in[4];
    const float* ln_b   = (const float*)d_in[5];
    const float* conv_w = (const float*)d_in[6];
    const float* conv_b = (const float*)d_in[7];
    const float* post_w = (const float*)d_in[8];
    const float* post_b = (const float*)d_in[9];
    float* out = (float*)d_out;

    char* w = (char*)d_ws;
    size_t off = 0;
    auto alloc = [&](size_t bytes) -> char* {
        char* p = w + off;
        off += (bytes + 255) & ~(size_t)255;
        return p;
    };
    unsigned long long* cnt64 = (unsigned long long*)alloc((size_t)N_NODES * 8);
    float* dinv   = (float*)alloc((size_t)N_NODES * 4);
    int*   rank   = (int*)alloc((size_t)N_EDGES * 4);
    int*   rowptr = (int*)alloc((size_t)(N_NODES + 1) * 4);
    int*   bsum   = (int*)alloc(256 * 4);
    int*   boff   = (int*)alloc(256 * 4);
    int2*  epack  = (int2*)alloc((size_t)EPACK_CAP * 8);
    unsigned short* Wt  = (unsigned short*)alloc((size_t)5 * 65536 * 2);
    unsigned short* Z16 = (unsigned short*)alloc((size_t)N_NODES * DIM * 2);
    unsigned short* ZWb = (unsigned short*)alloc((size_t)N_NODES * DIM * 2);
    unsigned short* Hbf = (unsigned short*)alloc((size_t)N_NODES * DIM * 2);

    hipMemsetAsync(cnt64, 0, (size_t)N_NODES * 8, stream);
    hipMemsetAsync(epack, 0, (size_t)EPACK_CAP * 8, stream);
    hist_kernel<<<N_EDGES / 256, 256, 0, stream>>>(dst, ew, cnt64, rank);
    scan_a_kernel<<<SCAN_B, 256, 0, stream>>>(cnt64, dinv, bsum);
    scan_b_kernel<<<1, 256, 0, stream>>>(bsum, boff, rowptr);
    scan_c_kernel<<<SCAN_B, 256, 0, stream>>>(cnt64, boff, rowptr);
    fill_kernel<<<N_EDGES / 256, 256, 0, stream>>>(src, dst, ew, dinv, rowptr, rank, epack);
    convw_kernel<<<(5 * 65536) / 256, 256, 0, stream>>>(conv_w, post_w, Wt);

    const int GEMM_GRID = (N_NODES + 63) / 64;  // 782
    ln_cast_kernel<<<N_NODES / 4, 256, 0, stream>>>(emb, ln_w, ln_b, Z16, Hbf);
    for (int l = 0; l < NLAYERS; ++l) {
        gemm_bf16_kernel<<<GEMM_GRID, 256, 0, stream>>>(Z16, Wt + (size_t)l * 65536, ZWb);
        int doLN = (l < NLAYERS - 1) ? 1 : 0;
        int writeH = (l < NLAYERS - 1) ? 1 : 0;
        const float* nlw = doLN ? (ln_w + (l + 1) * DIM) : nullptr;
        const float* nlb = doLN ? (ln_b + (l + 1) * DIM) : nullptr;
        agg_kernel<<<N_NODES / 4, 256, 0, stream>>>((const char*)ZWb, Hbf, conv_b + l * DIM,
                                                    rowptr, epack, dinv, nlw, nlb,
                                                    Z16, doLN, writeH);
    }
    gemm_f32_kernel<<<GEMM_GRID, 256, 0, stream>>>(Z16, Wt + (size_t)4 * 65536, out, post_b);
}

// Round 7
// 595.495 us; speedup vs baseline: 1.1540x; 1.1540x over previous
//
#include <hip/hip_runtime.h>
#include <hip/hip_bf16.h>

#define N_NODES 50000
#define N_EDGES 800000
#define DIM     256
#define NLAYERS 4
#define EPS     1e-5f
#define SCAN_B  196   // ceil(50000/256)
#define MASK40  ((1ULL << 40) - 1)
#define EPACK_CAP (N_EDGES + 15 * N_NODES + 32)   // CSR padded to 16

typedef __bf16 bf16x8 __attribute__((ext_vector_type(8)));
typedef float  f32x4  __attribute__((ext_vector_type(4)));
typedef float  f32x2  __attribute__((ext_vector_type(2)));
typedef unsigned short u16x8 __attribute__((ext_vector_type(8)));

__device__ __forceinline__ unsigned short f2b(float f) {
    __hip_bfloat16 h = __float2bfloat16(f);
    return __builtin_bit_cast(unsigned short, h);
}
__device__ __forceinline__ float b2f(unsigned short u) {
    unsigned int v = ((unsigned int)u) << 16;
    return __builtin_bit_cast(float, v);
}
__device__ __forceinline__ float gelu_exact(float x) {
    return 0.5f * x * (1.0f + erff(x * 0.70710678118654752f));
}
// pack 4 f32 -> 4 fp8 e4m3 (OCP on gfx950), RNE
__device__ __forceinline__ unsigned int pack_fp8x4(float a, float b, float c, float d) {
    int v = 0;
    v = __builtin_amdgcn_cvt_pk_fp8_f32(a, b, v, false);
    v = __builtin_amdgcn_cvt_pk_fp8_f32(c, d, v, true);
    return (unsigned int)v;
}

// ---- setup kernels ------------------------------------------------------
// One packed u64 atomic per edge: bits [40,64) = count, [0,40) = sum(w)*2^32.
// Returned old value's count field = this edge's rank within its dst row.
__global__ __launch_bounds__(256) void hist_kernel(const int* __restrict__ dst,
                                                   const float* __restrict__ w,
                                                   unsigned long long* __restrict__ cnt64,
                                                   int* __restrict__ rank) {
    int e = blockIdx.x * 256 + threadIdx.x;
    if (e >= N_EDGES) return;
    int d = dst[e];
    unsigned long long wfix = (unsigned long long)(w[e] * 4294967296.0f);
    unsigned long long old = atomicAdd(&cnt64[d], (1ULL << 40) | wfix);
    rank[e] = (int)(old >> 40);
}

// dinv = rsqrt(1 + sum(w)) ; block-sum of padded counts (pad to 16)
__global__ __launch_bounds__(256) void scan_a_kernel(const unsigned long long* __restrict__ cnt64,
                                                     float* __restrict__ dinv,
                                                     int* __restrict__ bsum) {
    __shared__ int l[256];
    int i = blockIdx.x * 256 + threadIdx.x;
    int pc = 0;
    if (i < N_NODES) {
        unsigned long long v = cnt64[i];
        int cnt = (int)(v >> 40);
        float sw = (float)(v & MASK40) * 2.3283064365386963e-10f;  // *2^-32
        dinv[i] = rsqrtf(1.0f + sw);
        pc = (cnt + 15) & ~15;
    }
    l[threadIdx.x] = pc;
    __syncthreads();
    for (int o = 128; o > 0; o >>= 1) {
        if (threadIdx.x < o) l[threadIdx.x] += l[threadIdx.x + o];
        __syncthreads();
    }
    if (threadIdx.x == 0) bsum[blockIdx.x] = l[0];
}

__global__ __launch_bounds__(256) void scan_b_kernel(const int* __restrict__ bsum,
                                                     int* __restrict__ boff,
                                                     int* __restrict__ rowptr) {
    __shared__ int l[256];
    int t = threadIdx.x;
    l[t] = (t < SCAN_B) ? bsum[t] : 0;
    __syncthreads();
    if (t == 0) {
        int run = 0;
        for (int j = 0; j < SCAN_B; ++j) { int v = l[j]; l[j] = run; run += v; }
        rowptr[N_NODES] = run;  // total padded entries
    }
    __syncthreads();
    boff[t] = l[t];
}

__global__ __launch_bounds__(256) void scan_c_kernel(const unsigned long long* __restrict__ cnt64,
                                                     const int* __restrict__ boff,
                                                     int* __restrict__ rowptr) {
    __shared__ int l[256];
    int i = blockIdx.x * 256 + threadIdx.x;
    int pc = 0;
    if (i < N_NODES) {
        int cnt = (int)(cnt64[i] >> 40);
        pc = (cnt + 15) & ~15;
    }
    l[threadIdx.x] = pc;
    __syncthreads();
    if (threadIdx.x == 0) {
        int run = 0;
        for (int j = 0; j < 256; ++j) { int v = l[j]; l[j] = run; run += v; }
    }
    __syncthreads();
    if (i < N_NODES) rowptr[i] = boff[blockIdx.x] + l[threadIdx.x];
}

// No atomics: position = rowptr[dst] + rank.  epack.x = src byte-offset (src*256, fp8 rows).
__global__ __launch_bounds__(256) void fill_kernel(const int* __restrict__ src,
                                                   const int* __restrict__ dst,
                                                   const float* __restrict__ w,
                                                   const float* __restrict__ dinv,
                                                   const int* __restrict__ rowptr,
                                                   const int* __restrict__ rank,
                                                   int2* __restrict__ epack) {
    int e = blockIdx.x * 256 + threadIdx.x;
    if (e >= N_EDGES) return;
    int s = src[e], d = dst[e];
    float c = dinv[s] * w[e] * dinv[d];
    int p = rowptr[d] + rank[e];
    epack[p] = make_int2(s << 8, __float_as_int(c));
}

// conv_w[l][k][n] (l<4) and post_w[k][n] (slot 4) -> Wt[l][n][k] bf16
__global__ __launch_bounds__(256) void convw_kernel(const float* __restrict__ conv_w,
                                                    const float* __restrict__ post_w,
                                                    unsigned short* __restrict__ Wt) {
    int idx = blockIdx.x * 256 + threadIdx.x;
    if (idx >= 5 * 65536) return;
    int m = idx >> 16;
    int r = idx & 65535;
    int n = r >> 8;
    int k = r & 255;
    float v = (m < 4) ? conv_w[m * 65536 + k * 256 + n] : post_w[k * 256 + n];
    Wt[idx] = f2b(v);
}

// ---- per-layer kernels --------------------------------------------------
// wave-per-row: Z = bf16(LN(emb)), Hbf = bf16(emb)  (used once)
__global__ __launch_bounds__(256) void ln_cast_kernel(const float* __restrict__ H,
                                                      const float* __restrict__ lnw,
                                                      const float* __restrict__ lnb,
                                                      unsigned short* __restrict__ Z,
                                                      unsigned short* __restrict__ Hbf) {
    int row = blockIdx.x * 4 + (threadIdx.x >> 6);
    int lane = threadIdx.x & 63;
    const float4 x = *(const float4*)(H + (size_t)row * DIM + lane * 4);
    float s = x.x + x.y + x.z + x.w;
    for (int o = 32; o > 0; o >>= 1) s += __shfl_xor(s, o);
    float mu = s * (1.0f / DIM);
    float d0 = x.x - mu, d1 = x.y - mu, d2 = x.z - mu, d3 = x.w - mu;
    float v = d0 * d0 + d1 * d1 + d2 * d2 + d3 * d3;
    for (int o = 32; o > 0; o >>= 1) v += __shfl_xor(v, o);
    float rs = rsqrtf(v * (1.0f / DIM) + EPS);
    const float4 ww = *(const float4*)(lnw + lane * 4);
    const float4 bb = *(const float4*)(lnb + lane * 4);
    ushort4 o4;
    o4.x = f2b(d0 * rs * ww.x + bb.x);
    o4.y = f2b(d1 * rs * ww.y + bb.y);
    o4.z = f2b(d2 * rs * ww.z + bb.z);
    o4.w = f2b(d3 * rs * ww.w + bb.w);
    *(ushort4*)(Z + (size_t)row * DIM + lane * 4) = o4;
    ushort4 h4;
    h4.x = f2b(x.x); h4.y = f2b(x.y); h4.z = f2b(x.z); h4.w = f2b(x.w);
    *(ushort4*)(Hbf + (size_t)row * DIM + lane * 4) = h4;
}

// ---- GEMM, transposed-operand form (weights = MFMA A-operand) -----------
// MODE 0: fp8 e4m3 output (for agg gather). MODE 1: fp32 out + bias.
template <int MODE>
__device__ __forceinline__ void gemm_body(const unsigned short* __restrict__ A,
                                          const unsigned short* __restrict__ Bt,
                                          void* __restrict__ Cout,
                                          const float* __restrict__ bias) {
    int tid = threadIdx.x;
    int wave = tid >> 6;
    int lane = tid & 63;
    int q = lane >> 4;
    int c16 = lane & 15;
    int mbase = blockIdx.x * 64;   // node base
    int cbase = wave * 64;         // channel base

    const unsigned short* aptr[4];
    #pragma unroll
    for (int nt = 0; nt < 4; ++nt) {
        int row = mbase + nt * 16 + c16;
        if (row >= N_NODES) row = N_NODES - 1;
        aptr[nt] = A + (size_t)row * DIM;
    }
    const unsigned short* wptr[4];
    #pragma unroll
    for (int ct = 0; ct < 4; ++ct)
        wptr[ct] = Bt + (size_t)(cbase + ct * 16 + c16) * DIM;

    f32x4 acc[4][4] = {};
    #pragma unroll 1
    for (int k0 = 0; k0 < DIM; k0 += 32) {
        bf16x8 nf[4], wf[4];
        #pragma unroll
        for (int nt = 0; nt < 4; ++nt)
            nf[nt] = __builtin_bit_cast(bf16x8, *(const u16x8*)(aptr[nt] + k0 + q * 8));
        #pragma unroll
        for (int ct = 0; ct < 4; ++ct)
            wf[ct] = __builtin_bit_cast(bf16x8, *(const u16x8*)(wptr[ct] + k0 + q * 8));
        #pragma unroll
        for (int nt = 0; nt < 4; ++nt)
            #pragma unroll
            for (int ct = 0; ct < 4; ++ct)
                acc[nt][ct] = __builtin_amdgcn_mfma_f32_16x16x32_bf16(wf[ct], nf[nt], acc[nt][ct], 0, 0, 0);
    }

    float4 bb[4];
    if (MODE == 1) {
        #pragma unroll
        for (int ct = 0; ct < 4; ++ct)
            bb[ct] = *(const float4*)(bias + cbase + ct * 16 + q * 4);
    }
    #pragma unroll
    for (int nt = 0; nt < 4; ++nt) {
        int node = mbase + nt * 16 + c16;
        if (node >= N_NODES) continue;
        #pragma unroll
        for (int ct = 0; ct < 4; ++ct) {
            int chan = cbase + ct * 16 + q * 4;
            if (MODE == 0) {
                unsigned char* C = (unsigned char*)Cout;
                unsigned int pv = pack_fp8x4(acc[nt][ct][0], acc[nt][ct][1],
                                             acc[nt][ct][2], acc[nt][ct][3]);
                *(unsigned int*)(C + (size_t)node * DIM + chan) = pv;
            } else {
                float* C = (float*)Cout;
                float4 o;
                o.x = acc[nt][ct][0] + bb[ct].x;
                o.y = acc[nt][ct][1] + bb[ct].y;
                o.z = acc[nt][ct][2] + bb[ct].z;
                o.w = acc[nt][ct][3] + bb[ct].w;
                *(float4*)(C + (size_t)node * DIM + chan) = o;
            }
        }
    }
}

__global__ __launch_bounds__(256) void gemm_fp8_kernel(const unsigned short* __restrict__ A,
                                                       const unsigned short* __restrict__ Bt,
                                                       unsigned char* __restrict__ C) {
    gemm_body<0>(A, Bt, C, nullptr);
}

__global__ __launch_bounds__(256) void gemm_f32_kernel(const unsigned short* __restrict__ A,
                                                       const unsigned short* __restrict__ Bt,
                                                       float* __restrict__ C,
                                                       const float* __restrict__ bias) {
    gemm_body<1>(A, Bt, C, bias);
}

// wave-per-node CSR aggregation over rows PADDED TO 16 (pads: off=0, coef=0).
// ZW rows are fp8 e4m3, 256 B. Half-wave (32 lanes x 8B) per edge, 8-deep
// chain per half -> 16 gathers in flight per wave. Residual H bf16 in place.
// Fused bias + exact GELU + residual + next-layer LN/cast -> Z16 bf16.
__global__ __launch_bounds__(256) void agg_kernel(const unsigned char* __restrict__ ZW,
                                                  unsigned short* __restrict__ Hbf,
                                                  const float* __restrict__ bias,
                                                  const int* __restrict__ rowptr,
                                                  const int2* __restrict__ epack,
                                                  const float* __restrict__ dinv,
                                                  const float* __restrict__ lnw,
                                                  const float* __restrict__ lnb,
                                                  unsigned short* __restrict__ Zout,
                                                  int doLN, int writeH) {
    int node = blockIdx.x * 4 + (threadIdx.x >> 6);
    int lane = threadIdx.x & 63;
    int g = lane >> 5;           // half id
    int colB = (lane & 31) * 8;  // byte offset of this lane's 8 fp8 elems

    float di = dinv[node];
    float scg = (g == 0) ? di * di : 0.0f;   // self-loop only in half 0
    const uint2 zs = *(const uint2*)(ZW + (size_t)node * DIM + colB);
    float a[8];
    {
        f32x2 p0 = __builtin_amdgcn_cvt_pk_f32_fp8(zs.x, false);
        f32x2 p1 = __builtin_amdgcn_cvt_pk_f32_fp8(zs.x, true);
        f32x2 p2 = __builtin_amdgcn_cvt_pk_f32_fp8(zs.y, false);
        f32x2 p3 = __builtin_amdgcn_cvt_pk_f32_fp8(zs.y, true);
        a[0] = scg * p0.x; a[1] = scg * p0.y; a[2] = scg * p1.x; a[3] = scg * p1.y;
        a[4] = scg * p2.x; a[5] = scg * p2.y; a[6] = scg * p3.x; a[7] = scg * p3.y;
    }

    int e0 = rowptr[node], e1 = rowptr[node + 1];
    for (int e = e0; e < e1; e += 16) {
        const int2* pp = epack + e + 8 * g;
        const int4 q0 = *(const int4*)pp;        // edges 0,1
        const int4 q1 = *(const int4*)(pp + 2);  // edges 2,3
        const int4 q2 = *(const int4*)(pp + 4);  // edges 4,5
        const int4 q3 = *(const int4*)(pp + 6);  // edges 6,7
        const uint2 v0 = *(const uint2*)(ZW + q0.x + colB);
        const uint2 v1 = *(const uint2*)(ZW + q0.z + colB);
        const uint2 v2 = *(const uint2*)(ZW + q1.x + colB);
        const uint2 v3 = *(const uint2*)(ZW + q1.z + colB);
        const uint2 v4 = *(const uint2*)(ZW + q2.x + colB);
        const uint2 v5 = *(const uint2*)(ZW + q2.z + colB);
        const uint2 v6 = *(const uint2*)(ZW + q3.x + colB);
        const uint2 v7 = *(const uint2*)(ZW + q3.z + colB);
        float c0 = __int_as_float(q0.y), c1 = __int_as_float(q0.w);
        float c2 = __int_as_float(q1.y), c3 = __int_as_float(q1.w);
        float c4 = __int_as_float(q2.y), c5 = __int_as_float(q2.w);
        float c6 = __int_as_float(q3.y), c7 = __int_as_float(q3.w);
        #pragma unroll
        for (int h = 0; h < 8; ++h) {
            uint2 vv; float cc;
            switch (h) {
                case 0: vv = v0; cc = c0; break;
                case 1: vv = v1; cc = c1; break;
                case 2: vv = v2; cc = c2; break;
                case 3: vv = v3; cc = c3; break;
                case 4: vv = v4; cc = c4; break;
                case 5: vv = v5; cc = c5; break;
                case 6: vv = v6; cc = c6; break;
                default: vv = v7; cc = c7; break;
            }
            f32x2 p0 = __builtin_amdgcn_cvt_pk_f32_fp8(vv.x, false);
            f32x2 p1 = __builtin_amdgcn_cvt_pk_f32_fp8(vv.x, true);
            f32x2 p2 = __builtin_amdgcn_cvt_pk_f32_fp8(vv.y, false);
            f32x2 p3 = __builtin_amdgcn_cvt_pk_f32_fp8(vv.y, true);
            a[0] += cc * p0.x; a[1] += cc * p0.y;
            a[2] += cc * p1.x; a[3] += cc * p1.y;
            a[4] += cc * p2.x; a[5] += cc * p2.y;
            a[6] += cc * p3.x; a[7] += cc * p3.y;
        }
    }
    // combine the two halves
    #pragma unroll
    for (int j = 0; j < 8; ++j) a[j] += __shfl_xor(a[j], 32);

    int col0 = (lane & 31) * 8;
    const float4 bb0 = *(const float4*)(bias + col0);
    const float4 bb1 = *(const float4*)(bias + col0 + 4);
    const u16x8 hv = *(const u16x8*)(Hbf + (size_t)node * DIM + col0);
    float o[8];
    o[0] = b2f(hv[0]) + gelu_exact(a[0] + bb0.x);
    o[1] = b2f(hv[1]) + gelu_exact(a[1] + bb0.y);
    o[2] = b2f(hv[2]) + gelu_exact(a[2] + bb0.z);
    o[3] = b2f(hv[3]) + gelu_exact(a[3] + bb0.w);
    o[4] = b2f(hv[4]) + gelu_exact(a[4] + bb1.x);
    o[5] = b2f(hv[5]) + gelu_exact(a[5] + bb1.y);
    o[6] = b2f(hv[6]) + gelu_exact(a[6] + bb1.z);
    o[7] = b2f(hv[7]) + gelu_exact(a[7] + bb1.w);

    if (writeH && g == 0) {
        u16x8 hw;
        #pragma unroll
        for (int j = 0; j < 8; ++j) hw[j] = f2b(o[j]);
        *(u16x8*)(Hbf + (size_t)node * DIM + col0) = hw;
    }

    float y[8];
    #pragma unroll
    for (int j = 0; j < 8; ++j) y[j] = o[j];
    if (doLN) {
        float s = 0.0f;
        #pragma unroll
        for (int j = 0; j < 8; ++j) s += o[j];
        for (int off = 16; off > 0; off >>= 1) s += __shfl_xor(s, off);
        float mu = s * (1.0f / DIM);
        float v = 0.0f;
        float d[8];
        #pragma unroll
        for (int j = 0; j < 8; ++j) { d[j] = o[j] - mu; v += d[j] * d[j]; }
        for (int off = 16; off > 0; off >>= 1) v += __shfl_xor(v, off);
        float rs = rsqrtf(v * (1.0f / DIM) + EPS);
        const float4 ww0 = *(const float4*)(lnw + col0);
        const float4 ww1 = *(const float4*)(lnw + col0 + 4);
        const float4 lb0 = *(const float4*)(lnb + col0);
        const float4 lb1 = *(const float4*)(lnb + col0 + 4);
        y[0] = d[0] * rs * ww0.x + lb0.x;
        y[1] = d[1] * rs * ww0.y + lb0.y;
        y[2] = d[2] * rs * ww0.z + lb0.z;
        y[3] = d[3] * rs * ww0.w + lb0.w;
        y[4] = d[4] * rs * ww1.x + lb1.x;
        y[5] = d[5] * rs * ww1.y + lb1.y;
        y[6] = d[6] * rs * ww1.z + lb1.z;
        y[7] = d[7] * rs * ww1.w + lb1.w;
    }
    if (g == 0) {
        u16x8 z;
        #pragma unroll
        for (int j = 0; j < 8; ++j) z[j] = f2b(y[j]);
        *(u16x8*)(Zout + (size_t)node * DIM + col0) = z;
    }
}

// ---- launch -------------------------------------------------------------
extern "C" void kernel_launch(void* const* d_in, const int* in_sizes, int n_in,
                              void* d_out, int out_size, void* d_ws, size_t ws_size,
                              hipStream_t stream) {
    const int*   ei     = (const int*)d_in[1];
    const int*   src    = ei;
    const int*   dst    = ei + N_EDGES;
    const float* ew     = (const float*)d_in[2];
    const float* emb    = (const float*)d_in[3];
    const float* ln_w   = (const float*)d_in[4];
    const float* ln_b   = (const float*)d_in[5];
    const float* conv_w = (const float*)d_in[6];
    const float* conv_b = (const float*)d_in[7];
    const float* post_w = (const float*)d_in[8];
    const float* post_b = (const float*)d_in[9];
    float* out = (float*)d_out;

    char* w = (char*)d_ws;
    size_t off = 0;
    auto alloc = [&](size_t bytes) -> char* {
        char* p = w + off;
        off += (bytes + 255) & ~(size_t)255;
        return p;
    };
    unsigned long long* cnt64 = (unsigned long long*)alloc((size_t)N_NODES * 8);
    float* dinv   = (float*)alloc((size_t)N_NODES * 4);
    int*   rank   = (int*)alloc((size_t)N_EDGES * 4);
    int*   rowptr = (int*)alloc((size_t)(N_NODES + 1) * 4);
    int*   bsum   = (int*)alloc(256 * 4);
    int*   boff   = (int*)alloc(256 * 4);
    int2*  epack  = (int2*)alloc((size_t)EPACK_CAP * 8);
    unsigned short* Wt  = (unsigned short*)alloc((size_t)5 * 65536 * 2);
    unsigned short* Z16 = (unsigned short*)alloc((size_t)N_NODES * DIM * 2);
    unsigned char*  ZW8 = (unsigned char*)alloc((size_t)N_NODES * DIM);
    unsigned short* Hbf = (unsigned short*)alloc((size_t)N_NODES * DIM * 2);

    hipMemsetAsync(cnt64, 0, (size_t)N_NODES * 8, stream);
    hipMemsetAsync(epack, 0, (size_t)EPACK_CAP * 8, stream);
    hist_kernel<<<N_EDGES / 256, 256, 0, stream>>>(dst, ew, cnt64, rank);
    scan_a_kernel<<<SCAN_B, 256, 0, stream>>>(cnt64, dinv, bsum);
    scan_b_kernel<<<1, 256, 0, stream>>>(bsum, boff, rowptr);
    scan_c_kernel<<<SCAN_B, 256, 0, stream>>>(cnt64, boff, rowptr);
    fill_kernel<<<N_EDGES / 256, 256, 0, stream>>>(src, dst, ew, dinv, rowptr, rank, epack);
    convw_kernel<<<(5 * 65536) / 256, 256, 0, stream>>>(conv_w, post_w, Wt);

    const int GEMM_GRID = (N_NODES + 63) / 64;  // 782
    ln_cast_kernel<<<N_NODES / 4, 256, 0, stream>>>(emb, ln_w, ln_b, Z16, Hbf);
    for (int l = 0; l < NLAYERS; ++l) {
        gemm_fp8_kernel<<<GEMM_GRID, 256, 0, stream>>>(Z16, Wt + (size_t)l * 65536, ZW8);
        int doLN = (l < NLAYERS - 1) ? 1 : 0;
        int writeH = (l < NLAYERS - 1) ? 1 : 0;
        const float* nlw = doLN ? (ln_w + (l + 1) * DIM) : nullptr;
        const float* nlb = doLN ? (ln_b + (l + 1) * DIM) : nullptr;
        agg_kernel<<<N_NODES / 4, 256, 0, stream>>>(ZW8, Hbf, conv_b + l * DIM,
                                                    rowptr, epack, dinv, nlw, nlb,
                                                    Z16, doLN, writeH);
    }
    gemm_f32_kernel<<<GEMM_GRID, 256, 0, stream>>>(Z16, Wt + (size_t)4 * 65536, out, post_b);
}